// Round 17
// baseline (228.732 us; speedup 1.0000x reference)
//
#include <hip/hip_runtime.h>
#include <hip/hip_cooperative_groups.h>
#include <hip/hip_bf16.h>
#include <math.h>

#define NN 8192
#define DD 128
#define BIGF 3.402823466e+38f

namespace cg = cooperative_groups;

typedef __attribute__((ext_vector_type(8))) short short8;
typedef __attribute__((ext_vector_type(4))) float f32x4;

static __device__ __forceinline__ unsigned short bfc(float f) {
    return __bfloat16_as_ushort(__float2bfloat16(f));
}

// ================= device helpers shared by mono + fallback =================

// prep unit: one 8-row octet of one matrix, 256 threads
static __device__ __forceinline__ void prep_unit(const float* __restrict__ x,
                                                 __hip_bfloat16* __restrict__ xb,
                                                 float* __restrict__ nrm,
                                                 int oct, int tid) {
    const int sub = tid >> 5, ch = tid & 31;
    const int row = oct * 8 + sub;
    const float4 v = *(const float4*)(x + (size_t)row * DD + ch * 4);
    float s = v.x * v.x + v.y * v.y + v.z * v.z + v.w * v.w;
    uint2 pk;
    pk.x = ((unsigned)bfc(v.y) << 16) | bfc(v.x);
    pk.y = ((unsigned)bfc(v.w) << 16) | bfc(v.z);
    *(uint2*)(xb + (size_t)row * DD + ch * 4) = pk;
#pragma unroll
    for (int off = 16; off >= 1; off >>= 1) s += __shfl_xor(s, off, 64);
    if (ch == 0) nrm[row] = s;
}

// R11 dist tile body (the proven 44-us structure): 128x128 tile, 4 waves 2x2,
// K in two 64-wide phases, XOR-swizzled 32KB LDS, zero atomics.
static __device__ __forceinline__ void dist_tile(
    int bx, int by, char* lds, float (*rmbuf)[128], float (*cmbuf)[128],
    float* tbuf,
    const __hip_bfloat16* __restrict__ Ab, const __hip_bfloat16* __restrict__ Bb,
    const float* __restrict__ nA, const float* __restrict__ nB,
    float* __restrict__ rowpart, float* __restrict__ colpart,
    float* __restrict__ totpart, int tid) {
    char* ldsA = lds;
    char* ldsB = lds + 16384;
    const int rowBase = by * 128;
    const int colBase = bx * 128;
    const unsigned short* aG = (const unsigned short*)Ab + (size_t)rowBase * DD;
    const unsigned short* bG = (const unsigned short*)Bb + (size_t)colBase * DD;
    const int l = tid & 63, wid = tid >> 6;
    const int wr = wid >> 1, wc = wid & 1;
    const int g = l >> 4, c = l & 15;

    f32x4 acc[4][4];
#pragma unroll
    for (int mi = 0; mi < 4; ++mi)
#pragma unroll
        for (int ni = 0; ni < 4; ++ni) acc[mi][ni] = (f32x4)0.f;

#pragma unroll
    for (int p = 0; p < 2; ++p) {
        if (p) __syncthreads();
#pragma unroll
        for (int it = 0; it < 4; ++it) {
            int idx = tid + 256 * it;
            int r = idx >> 3;
            int c16 = idx & 7;
            int dst = r * 128 + ((c16 * 16) ^ ((r & 7) << 4));
            *(short8*)(ldsA + dst) = *(const short8*)(aG + r * DD + p * 64 + c16 * 8);
            *(short8*)(ldsB + dst) = *(const short8*)(bG + r * DD + p * 64 + c16 * 8);
        }
        __syncthreads();
#pragma unroll
        for (int kk = 0; kk < 2; ++kk) {
            short8 af[4], bf[4];
            const int kbyte = kk * 64 + g * 16;
#pragma unroll
            for (int mi = 0; mi < 4; ++mi) {
                int r = wr * 64 + mi * 16 + c;
                af[mi] = *(const short8*)(ldsA + r * 128 + (kbyte ^ ((r & 7) << 4)));
                int r2 = wc * 64 + mi * 16 + c;
                bf[mi] = *(const short8*)(ldsB + r2 * 128 + (kbyte ^ ((r2 & 7) << 4)));
            }
#pragma unroll
            for (int mi = 0; mi < 4; ++mi)
#pragma unroll
                for (int ni = 0; ni < 4; ++ni)
                    acc[mi][ni] = __builtin_amdgcn_mfma_f32_16x16x32_bf16(
                        af[mi], bf[ni], acc[mi][ni], 0, 0, 0);
        }
    }

    const int row0 = rowBase + wr * 64;
    const int col0 = colBase + wc * 64;
    float nbc[4];
#pragma unroll
    for (int ni = 0; ni < 4; ++ni) nbc[ni] = nB[col0 + ni * 16 + c];

    float colm2[4] = {BIGF, BIGF, BIGF, BIGF};
    f32x4 tot4 = (f32x4)0.f;
#pragma unroll
    for (int mi = 0; mi < 4; ++mi) {
        const f32x4 na4 = *(const f32x4*)(nA + row0 + mi * 16 + g * 4);
        float rowm2[4] = {BIGF, BIGF, BIGF, BIGF};
#pragma unroll
        for (int ni = 0; ni < 4; ++ni) {
            f32x4 a = acc[mi][ni];
#pragma unroll
            for (int reg = 0; reg < 4; ++reg) {
                float d2 = fmaf(-2.0f, a[reg], na4[reg] + nbc[ni]);
                rowm2[reg] = fminf(rowm2[reg], d2);
                colm2[ni] = fminf(colm2[ni], d2);
                tot4[reg] += __builtin_amdgcn_sqrtf(fmaxf(d2, 0.f));
            }
        }
#pragma unroll
        for (int reg = 0; reg < 4; ++reg) {
            float m = rowm2[reg];
            m = fminf(m, __shfl_xor(m, 1, 64));
            m = fminf(m, __shfl_xor(m, 2, 64));
            m = fminf(m, __shfl_xor(m, 4, 64));
            m = fminf(m, __shfl_xor(m, 8, 64));
            if (c == 0) rmbuf[wc][wr * 64 + mi * 16 + g * 4 + reg] = m;
        }
    }
#pragma unroll
    for (int ni = 0; ni < 4; ++ni) {
        float m = colm2[ni];
        m = fminf(m, __shfl_xor(m, 16, 64));
        m = fminf(m, __shfl_xor(m, 32, 64));
        if (g == 0) cmbuf[wr][wc * 64 + ni * 16 + c] = m;
    }
    float tot = (tot4[0] + tot4[1]) + (tot4[2] + tot4[3]);
#pragma unroll
    for (int off = 32; off >= 1; off >>= 1) tot += __shfl_xor(tot, off, 64);
    if (l == 0) tbuf[wid] = tot;
    __syncthreads();

    if (tid < 128) {
        rowpart[(size_t)bx * NN + rowBase + tid] = fminf(rmbuf[0][tid], rmbuf[1][tid]);
    } else if (tid < 256) {
        int j = tid - 128;
        colpart[(size_t)by * NN + colBase + j] = fminf(cmbuf[0][j], cmbuf[1][j]);
    }
    if (tid == 0)
        totpart[by * 64 + bx] = tbuf[0] + tbuf[1] + tbuf[2] + tbuf[3];
}

// ================= mono: single cooperative kernel (P -> D -> F) =================
__global__ __launch_bounds__(256, 4) void mono_kernel(
    const float* __restrict__ A32, const float* __restrict__ B32,
    __hip_bfloat16* __restrict__ Abf, __hip_bfloat16* __restrict__ Bbf,
    float* __restrict__ nA, float* __restrict__ nB,
    float* __restrict__ rowpart, float* __restrict__ colpart,
    float* __restrict__ totpart, float* __restrict__ out, int NBK) {
    __shared__ char lds[32768];
    __shared__ float rmbuf[2][128];
    __shared__ float cmbuf[2][128];
    __shared__ float tbuf[4];
    cg::grid_group grid = cg::this_grid();
    const int bid = blockIdx.x;
    const int tid = threadIdx.x;

    // ---- Phase P: fp32 -> bf16 + norms (grid-stride, 2048 octet-units) ----
    for (int u = bid; u < 2048; u += NBK) {
        const int mat = u >> 10, oct = u & 1023;
        prep_unit(mat ? B32 : A32, mat ? Bbf : Abf, mat ? nB : nA, oct, tid);
    }
    if (bid == 0 && tid == 0) out[0] = 1.0f - 1.0f / 8192.0f;  // loss base term
    grid.sync();

    // ---- Phase D: distance tiles (grid-stride, 4096 tiles, XCD-swizzled) ----
    for (int t = bid; t < 4096; t += NBK) {
        const int swz = (t & 7) * 512 + (t >> 3);   // bijective, 8 XCD chunks
        dist_tile(swz & 63, swz >> 6, lds, rmbuf, cmbuf, tbuf,
                  Abf, Bbf, nA, nB, rowpart, colpart, totpart, tid);
        __syncthreads();   // all waves past partial-store reads before re-staging
    }
    grid.sync();

    // ---- Phase F: fold 64-way partials, <=64 atomicAdds into out ----
    for (int u = bid; u < 64; u += NBK) {
        const int idx = u * 256 + tid;           // 0..16383
        const int j = (idx < NN) ? idx : idx - NN;
        const float* p = (idx < NN) ? rowpart : colpart;
        float m = BIGF;
#pragma unroll 8
        for (int k = 0; k < 64; ++k) m = fminf(m, p[(size_t)k * NN + j]);
        float contrib = -__builtin_amdgcn_sqrtf(fmaxf(m, 0.f)) * (1.0f / 16384.0f);
        if (u < 16) contrib += totpart[u * 256 + tid] * (1.0f / 67108864.0f);
#pragma unroll
        for (int off = 32; off >= 1; off >>= 1) contrib += __shfl_xor(contrib, off, 64);
        if ((tid & 63) == 0) tbuf[tid >> 6] = contrib;
        __syncthreads();
        if (tid == 0) atomicAdd(out, tbuf[0] + tbuf[1] + tbuf[2] + tbuf[3]);
        __syncthreads();
    }
}

// ================= fallback 4-kernel pipeline (R11 structure) =================
__global__ __launch_bounds__(256) void prep_kernel(const float* __restrict__ A,
                                                   const float* __restrict__ B,
                                                   __hip_bfloat16* __restrict__ Abf,
                                                   __hip_bfloat16* __restrict__ Bbf,
                                                   float* __restrict__ nA,
                                                   float* __restrict__ nB,
                                                   float* __restrict__ out) {
    if (blockIdx.x == 0 && blockIdx.y == 0 && threadIdx.x == 0)
        out[0] = 1.0f - 1.0f / 8192.0f;
    prep_unit(blockIdx.y ? B : A, blockIdx.y ? Bbf : Abf, blockIdx.y ? nB : nA,
              blockIdx.x, threadIdx.x);
}

__global__ __launch_bounds__(256, 4) void dist_kernel(
    const __hip_bfloat16* __restrict__ Ab, const __hip_bfloat16* __restrict__ Bb,
    const float* __restrict__ nA, const float* __restrict__ nB,
    float* __restrict__ rowpart, float* __restrict__ colpart,
    float* __restrict__ totpart) {
    __shared__ char lds[32768];
    __shared__ float rmbuf[2][128];
    __shared__ float cmbuf[2][128];
    __shared__ float tbuf[4];
    const int lin = blockIdx.y * 64 + blockIdx.x;
    const int swz = (lin & 7) * 512 + (lin >> 3);
    dist_tile(swz & 63, swz >> 6, lds, rmbuf, cmbuf, tbuf,
              Ab, Bb, nA, nB, rowpart, colpart, totpart, threadIdx.x);
}

__global__ __launch_bounds__(256) void fin1_kernel(const float* __restrict__ rowpart,
                                                   const float* __restrict__ colpart,
                                                   const float* __restrict__ totpart,
                                                   float* __restrict__ finpart) {
    const int idx = blockIdx.x * 256 + threadIdx.x;
    const int j = (idx < NN) ? idx : idx - NN;
    const float* p = (idx < NN) ? rowpart : colpart;
    float m = BIGF;
#pragma unroll 8
    for (int k = 0; k < 64; ++k) m = fminf(m, p[(size_t)k * NN + j]);
    float contrib = -__builtin_amdgcn_sqrtf(fmaxf(m, 0.f)) * (1.0f / 16384.0f);
    if (blockIdx.x < 16)
        contrib += totpart[blockIdx.x * 256 + threadIdx.x] * (1.0f / 67108864.0f);
#pragma unroll
    for (int off = 32; off >= 1; off >>= 1) contrib += __shfl_xor(contrib, off, 64);
    __shared__ float red[4];
    if ((threadIdx.x & 63) == 0) red[threadIdx.x >> 6] = contrib;
    __syncthreads();
    if (threadIdx.x == 0)
        finpart[blockIdx.x] = red[0] + red[1] + red[2] + red[3];
}

__global__ __launch_bounds__(64) void fin2_kernel(const float* __restrict__ finpart,
                                                  float* __restrict__ out) {
    float s = finpart[threadIdx.x];
#pragma unroll
    for (int off = 32; off >= 1; off >>= 1) s += __shfl_xor(s, off, 64);
    if (threadIdx.x == 0) out[0] += s;   // out holds the base term from prep
}

extern "C" void kernel_launch(void* const* d_in, const int* in_sizes, int n_in,
                              void* d_out, int out_size, void* d_ws, size_t ws_size,
                              hipStream_t stream) {
    const float* A = (const float*)d_in[0];
    const float* B = (const float*)d_in[1];
    char* ws = (char*)d_ws;

    const size_t MB = 1024 * 1024;
    __hip_bfloat16* Abf = (__hip_bfloat16*)(ws);                  // 2 MB
    __hip_bfloat16* Bbf = (__hip_bfloat16*)(ws + 2 * MB);         // 2 MB
    float* nA      = (float*)(ws + 4 * MB);                       // 32 KB
    float* nB      = (float*)(ws + 4 * MB + 32768);               // 32 KB
    float* rowpart = (float*)(ws + 4 * MB + 65536);               // 2 MB
    float* colpart = (float*)(ws + 6 * MB + 65536);               // 2 MB
    float* totpart = (float*)(ws + 8 * MB + 65536);               // 16 KB
    float* finpart = (float*)(ws + 8 * MB + 65536 + 16384);       // 256 B
    float* outp    = (float*)d_out;

    // size the cooperative grid from the occupancy query (guaranteed co-resident)
    int maxb = 0;
    (void)hipOccupancyMaxActiveBlocksPerMultiprocessor(&maxb, mono_kernel, 256, 0);
    int nbk = (maxb > 0) ? maxb * 256 : 512;
    if (nbk > 1024) nbk = 1024;
    nbk &= ~7;           // multiple of 8 keeps the XCD chunking clean
    if (nbk < 64) nbk = 64;

    void* args[] = {(void*)&A, (void*)&B, (void*)&Abf, (void*)&Bbf,
                    (void*)&nA, (void*)&nB, (void*)&rowpart, (void*)&colpart,
                    (void*)&totpart, (void*)&outp, (void*)&nbk};
    hipError_t e = hipLaunchCooperativeKernel((void*)mono_kernel, dim3(nbk),
                                              dim3(256), args, 0, stream);
    if (e != hipSuccess) {
        (void)hipGetLastError();   // clear; fall back to the proven 4-kernel path
        dim3 pgrid(NN / 8, 2);
        prep_kernel<<<pgrid, 256, 0, stream>>>(A, B, Abf, Bbf, nA, nB, outp);
        dim3 grid(NN / 128, NN / 128);
        dist_kernel<<<grid, 256, 0, stream>>>(Abf, Bbf, nA, nB, rowpart, colpart,
                                              totpart);
        fin1_kernel<<<64, 256, 0, stream>>>(rowpart, colpart, totpart, finpart);
        fin2_kernel<<<1, 64, 0, stream>>>(finpart, outp);
    }
}

// Round 18
// 67.976 us; speedup vs baseline: 3.3649x; 3.3649x over previous
//
#include <hip/hip_runtime.h>
#include <hip/hip_bf16.h>
#include <math.h>

#define NN 8192
#define DD 128
#define BIGF 3.402823466e+38f

typedef __attribute__((ext_vector_type(8))) short short8;
typedef __attribute__((ext_vector_type(4))) float f32x4;

static __device__ __forceinline__ unsigned short bfc(float f) {
    return __bfloat16_as_ushort(__float2bfloat16(f));
}

// ---------------- prep: fp32 -> bf16 + exact fp32 row norms + out base ----------------
__global__ __launch_bounds__(256) void prep_kernel(const float* __restrict__ A,
                                                   const float* __restrict__ B,
                                                   __hip_bfloat16* __restrict__ Abf,
                                                   __hip_bfloat16* __restrict__ Bbf,
                                                   float* __restrict__ na,
                                                   float* __restrict__ nb,
                                                   float* __restrict__ out) {
    if (blockIdx.x == 0 && blockIdx.y == 0 && threadIdx.x == 0)
        out[0] = 1.0f - 1.0f / 8192.0f;   // loss base term (replay-safe rewrite)
    const float* x = blockIdx.y ? B : A;
    __hip_bfloat16* xb = blockIdx.y ? Bbf : Abf;
    float* norm = blockIdx.y ? nb : na;
    const int sub = threadIdx.x >> 5;
    const int ch  = threadIdx.x & 31;
    const int row = blockIdx.x * 8 + sub;
    const float4 v = *(const float4*)(x + (size_t)row * DD + ch * 4);
    float s = v.x * v.x + v.y * v.y + v.z * v.z + v.w * v.w;
    uint2 pk;
    pk.x = ((unsigned)bfc(v.y) << 16) | bfc(v.x);
    pk.y = ((unsigned)bfc(v.w) << 16) | bfc(v.z);
    *(uint2*)(xb + (size_t)row * DD + ch * 4) = pk;
#pragma unroll
    for (int off = 16; off >= 1; off >>= 1) s += __shfl_xor(s, off, 64);
    if (ch == 0) norm[row] = s;
}

// ---------------- fused MFMA distance pass (R11 base + true T14 prefetch) ----------------
// loss = 1 - 1/8192 + T/(N*M) - (P_r + P_c)/16384 (hinge never clips: d >= pos).
// Mins on d^2 (sqrt monotone). 128x128 tile, 4 waves (2x2), 64x64/wave.
// ALL 16 staging loads (both 64-wide K phases) are issued up front into regs;
// phase-0 LDS write waits only on its own 8 (counted vmcnt), phase-1's latency
// hides under phase-0 compute. Same 4 barriers as R11. (256,3): ~170-reg cap so
// the 64 prefetch VGPRs fit without spill (R13's 512/(,4) clamp spilled them).
// Zero atomics in hot path (R10); bijective XCD swizzle (R11).
__global__ __launch_bounds__(256, 3) void dist_fused(
    const __hip_bfloat16* __restrict__ Ab, const __hip_bfloat16* __restrict__ Bb,
    const float* __restrict__ na, const float* __restrict__ nb,
    float* __restrict__ rowpart, float* __restrict__ colpart,
    float* __restrict__ totpart) {
    __shared__ char lds[32768];
    __shared__ float rmbuf[2][128];   // [wc][row_in_block]
    __shared__ float cmbuf[2][128];   // [wr][col_in_block]
    __shared__ float tbuf[4];
    char* ldsA = lds;
    char* ldsB = lds + 16384;
    const int tid = threadIdx.x;
    const int l = tid & 63, wid = tid >> 6;
    const int wr = wid >> 1, wc = wid & 1;   // wave 64x64 sub-tile
    const int g = l >> 4, c = l & 15;

    // bijective XCD swizzle (4096 blocks, 8 XCDs)
    const int lin = blockIdx.y * 64 + blockIdx.x;
    const int swz = (lin & 7) * 512 + (lin >> 3);
    const int bx = swz & 63, by = swz >> 6;
    const int rowBase = by * 128;
    const int colBase = bx * 128;

    const unsigned short* aG = (const unsigned short*)Ab + (size_t)rowBase * DD;
    const unsigned short* bG = (const unsigned short*)Bb + (size_t)colBase * DD;

    // per-thread staging geometry: it-chunk idx -> row r, 16B chunk c16
    // (r = idx>>3 covers rows 0..127, c16 = idx&7 covers one 64-col phase)

    // ---- issue ALL staging loads up front: phase 0 then phase 1 ----
    short8 a0[4], b0[4], a1[4], b1[4];
#pragma unroll
    for (int it = 0; it < 4; ++it) {
        int idx = tid + 256 * it, r = idx >> 3, c16 = idx & 7;
        a0[it] = *(const short8*)(aG + r * DD + c16 * 8);
        b0[it] = *(const short8*)(bG + r * DD + c16 * 8);
    }
#pragma unroll
    for (int it = 0; it < 4; ++it) {
        int idx = tid + 256 * it, r = idx >> 3, c16 = idx & 7;
        a1[it] = *(const short8*)(aG + r * DD + 64 + c16 * 8);
        b1[it] = *(const short8*)(bG + r * DD + 64 + c16 * 8);
    }
    // ---- phase-0 LDS write (waits only on the first 8 loads) ----
#pragma unroll
    for (int it = 0; it < 4; ++it) {
        int idx = tid + 256 * it, r = idx >> 3, c16 = idx & 7;
        int dst = r * 128 + ((c16 * 16) ^ ((r & 7) << 4));
        *(short8*)(ldsA + dst) = a0[it];
        *(short8*)(ldsB + dst) = b0[it];
    }
    __syncthreads();

    f32x4 acc[4][4];
#pragma unroll
    for (int mi = 0; mi < 4; ++mi)
#pragma unroll
        for (int ni = 0; ni < 4; ++ni) acc[mi][ni] = (f32x4)0.f;

#define COMPUTE_PHASE() do {                                                      \
    _Pragma("unroll")                                                             \
    for (int kk = 0; kk < 2; ++kk) {                                              \
        short8 af[4], bf[4];                                                      \
        const int kbyte = kk * 64 + g * 16;                                       \
        _Pragma("unroll")                                                         \
        for (int mi = 0; mi < 4; ++mi) {                                          \
            int r = wr * 64 + mi * 16 + c;                                        \
            af[mi] = *(const short8*)(ldsA + r * 128 + (kbyte ^ ((r & 7) << 4))); \
            int r2 = wc * 64 + mi * 16 + c;                                       \
            bf[mi] = *(const short8*)(ldsB + r2 * 128 + (kbyte ^ ((r2 & 7) << 4)));\
        }                                                                         \
        _Pragma("unroll")                                                         \
        for (int mi = 0; mi < 4; ++mi)                                            \
            _Pragma("unroll")                                                     \
            for (int ni = 0; ni < 4; ++ni)                                        \
                acc[mi][ni] = __builtin_amdgcn_mfma_f32_16x16x32_bf16(            \
                    af[mi], bf[ni], acc[mi][ni], 0, 0, 0);                        \
    } } while (0)

    COMPUTE_PHASE();      // phase 0 (phase-1 loads still in flight)
    __syncthreads();      // all waves done reading phase-0 LDS
#pragma unroll
    for (int it = 0; it < 4; ++it) {
        int idx = tid + 256 * it, r = idx >> 3, c16 = idx & 7;
        int dst = r * 128 + ((c16 * 16) ^ ((r & 7) << 4));
        *(short8*)(ldsA + dst) = a1[it];
        *(short8*)(ldsB + dst) = b1[it];
    }
    __syncthreads();
    COMPUTE_PHASE();      // phase 1
#undef COMPUTE_PHASE

    // out_row = row0 + mi*16 + g*4 + reg ; out_col = col0 + ni*16 + c
    const int row0 = rowBase + wr * 64;
    const int col0 = colBase + wc * 64;

    float nbc[4];
#pragma unroll
    for (int ni = 0; ni < 4; ++ni) nbc[ni] = nb[col0 + ni * 16 + c];

    float colm2[4] = {BIGF, BIGF, BIGF, BIGF};
    f32x4 tot4 = (f32x4)0.f;
#pragma unroll
    for (int mi = 0; mi < 4; ++mi) {
        const f32x4 na4 = *(const f32x4*)(na + row0 + mi * 16 + g * 4);
        float rowm2[4] = {BIGF, BIGF, BIGF, BIGF};
#pragma unroll
        for (int ni = 0; ni < 4; ++ni) {
            f32x4 a = acc[mi][ni];
#pragma unroll
            for (int reg = 0; reg < 4; ++reg) {
                float d2 = fmaf(-2.0f, a[reg], na4[reg] + nbc[ni]);
                rowm2[reg] = fminf(rowm2[reg], d2);
                colm2[ni] = fminf(colm2[ni], d2);
                tot4[reg] += __builtin_amdgcn_sqrtf(fmaxf(d2, 0.f));
            }
        }
#pragma unroll
        for (int reg = 0; reg < 4; ++reg) {
            float m = rowm2[reg];
            m = fminf(m, __shfl_xor(m, 1, 64));
            m = fminf(m, __shfl_xor(m, 2, 64));
            m = fminf(m, __shfl_xor(m, 4, 64));
            m = fminf(m, __shfl_xor(m, 8, 64));
            if (c == 0) rmbuf[wc][wr * 64 + mi * 16 + g * 4 + reg] = m;
        }
    }
#pragma unroll
    for (int ni = 0; ni < 4; ++ni) {
        float m = colm2[ni];
        m = fminf(m, __shfl_xor(m, 16, 64));
        m = fminf(m, __shfl_xor(m, 32, 64));
        if (g == 0) cmbuf[wr][wc * 64 + ni * 16 + c] = m;
    }
    float tot = (tot4[0] + tot4[1]) + (tot4[2] + tot4[3]);
#pragma unroll
    for (int off = 32; off >= 1; off >>= 1) tot += __shfl_xor(tot, off, 64);
    if (l == 0) tbuf[wid] = tot;
    __syncthreads();

    // plain disjoint stores - no atomics anywhere
    if (tid < 128) {
        rowpart[(size_t)bx * NN + rowBase + tid] = fminf(rmbuf[0][tid], rmbuf[1][tid]);
    } else if (tid < 256) {
        int j = tid - 128;
        colpart[(size_t)by * NN + colBase + j] = fminf(cmbuf[0][j], cmbuf[1][j]);
    }
    if (tid == 0)
        totpart[by * 64 + bx] = tbuf[0] + tbuf[1] + tbuf[2] + tbuf[3];
}

// ---------------- fin: fold 64-way partials; one atomicAdd per block ----------------
// (64 float atomicAdds into out: ordering jitter ~1 ulp << 8.4e-2 threshold.
//  Visibility of dist's plain stores is by kernel boundary - no handshakes, R15 lesson.)
__global__ __launch_bounds__(256) void fin_kernel(const float* __restrict__ rowpart,
                                                  const float* __restrict__ colpart,
                                                  const float* __restrict__ totpart,
                                                  float* __restrict__ out) {
    const int idx = blockIdx.x * 256 + threadIdx.x;   // 0..16383
    const int j = (idx < NN) ? idx : idx - NN;
    const float* p = (idx < NN) ? rowpart : colpart;
    float m = BIGF;
#pragma unroll 8
    for (int k = 0; k < 64; ++k) m = fminf(m, p[(size_t)k * NN + j]);
    float contrib = -__builtin_amdgcn_sqrtf(fmaxf(m, 0.f)) * (1.0f / 16384.0f);
    if (blockIdx.x < 16)
        contrib += totpart[blockIdx.x * 256 + threadIdx.x] * (1.0f / 67108864.0f);
#pragma unroll
    for (int off = 32; off >= 1; off >>= 1) contrib += __shfl_xor(contrib, off, 64);
    __shared__ float red[4];
    if ((threadIdx.x & 63) == 0) red[threadIdx.x >> 6] = contrib;
    __syncthreads();
    if (threadIdx.x == 0)
        atomicAdd(out, red[0] + red[1] + red[2] + red[3]);
}

extern "C" void kernel_launch(void* const* d_in, const int* in_sizes, int n_in,
                              void* d_out, int out_size, void* d_ws, size_t ws_size,
                              hipStream_t stream) {
    const float* A = (const float*)d_in[0];
    const float* B = (const float*)d_in[1];
    char* ws = (char*)d_ws;

    const size_t MB = 1024 * 1024;
    __hip_bfloat16* Abf = (__hip_bfloat16*)(ws);                  // 2 MB
    __hip_bfloat16* Bbf = (__hip_bfloat16*)(ws + 2 * MB);         // 2 MB
    float* na      = (float*)(ws + 4 * MB);                       // 32 KB
    float* nb      = (float*)(ws + 4 * MB + 32768);               // 32 KB
    float* rowpart = (float*)(ws + 4 * MB + 65536);               // 2 MB  [ct][8192]
    float* colpart = (float*)(ws + 6 * MB + 65536);               // 2 MB  [rt][8192]
    float* totpart = (float*)(ws + 8 * MB + 65536);               // 16 KB

    dim3 pgrid(NN / 8, 2);
    prep_kernel<<<pgrid, 256, 0, stream>>>(A, B, Abf, Bbf, na, nb, (float*)d_out);

    dim3 grid(NN / 128, NN / 128);
    dist_fused<<<grid, 256, 0, stream>>>(Abf, Bbf, na, nb, rowpart, colpart, totpart);

    fin_kernel<<<64, 256, 0, stream>>>(rowpart, colpart, totpart, (float*)d_out);
}

// Round 19
// 63.763 us; speedup vs baseline: 3.5872x; 1.0661x over previous
//
#include <hip/hip_runtime.h>
#include <hip/hip_bf16.h>
#include <math.h>

#define NN 8192
#define DD 128
#define BIGF 3.402823466e+38f

typedef __attribute__((ext_vector_type(8))) short short8;
typedef __attribute__((ext_vector_type(4))) float f32x4;

static __device__ __forceinline__ unsigned short bfc(float f) {
    return __bfloat16_as_ushort(__float2bfloat16(f));
}

// ---------------- prep: fp32 -> bf16 + exact fp32 row norms + out base ----------------
__global__ __launch_bounds__(256) void prep_kernel(const float* __restrict__ A,
                                                   const float* __restrict__ B,
                                                   __hip_bfloat16* __restrict__ Abf,
                                                   __hip_bfloat16* __restrict__ Bbf,
                                                   float* __restrict__ na,
                                                   float* __restrict__ nb,
                                                   float* __restrict__ out) {
    if (blockIdx.x == 0 && blockIdx.y == 0 && threadIdx.x == 0)
        out[0] = 1.0f - 1.0f / 8192.0f;   // loss base term (replay-safe rewrite)
    const float* x = blockIdx.y ? B : A;
    __hip_bfloat16* xb = blockIdx.y ? Bbf : Abf;
    float* norm = blockIdx.y ? nb : na;
    const int sub = threadIdx.x >> 5;
    const int ch  = threadIdx.x & 31;
    const int row = blockIdx.x * 8 + sub;
    const float4 v = *(const float4*)(x + (size_t)row * DD + ch * 4);
    float s = v.x * v.x + v.y * v.y + v.z * v.z + v.w * v.w;
    uint2 pk;
    pk.x = ((unsigned)bfc(v.y) << 16) | bfc(v.x);
    pk.y = ((unsigned)bfc(v.w) << 16) | bfc(v.z);
    *(uint2*)(xb + (size_t)row * DD + ch * 4) = pk;
#pragma unroll
    for (int off = 16; off >= 1; off >>= 1) s += __shfl_xor(s, off, 64);
    if (ch == 0) norm[row] = s;
}

// ---------------- fused MFMA distance pass (exact R11 body - measured best) ----------------
// loss = 1 - 1/8192 + T/(N*M) - (P_r + P_c)/16384 (hinge never clips: d >= pos).
// Mins tracked on d^2 (sqrt monotone). 128x128 tile, 4 waves (2x2), 64x64/wave.
// K in two 64-wide phases -> 32 KB tile LDS + dedicated 2.1 KB epilogue buffers.
// XOR-swizzled staging: 0 bank conflicts measured. Zero atomics in the hot path
// (R10: 1M device-scope atomics = 21 MB coherence-point writes, the original
// poison). Bijective XCD swizzle: each XCD sees 8 row-panels x all col-panels,
// L2-resident. 18-round ledger: this 2-phase compiler-scheduled structure beats
// global_load_lds (R7 3x), LDS-free scattered (R8), manual dbuf (R9), 256-tall
// tile (R13), reg-prefetch (R13/R18), coop mono-kernel (R17 3.4x).
__global__ __launch_bounds__(256, 4) void dist_fused(
    const __hip_bfloat16* __restrict__ Ab, const __hip_bfloat16* __restrict__ Bb,
    const float* __restrict__ na, const float* __restrict__ nb,
    float* __restrict__ rowpart, float* __restrict__ colpart,
    float* __restrict__ totpart) {
    __shared__ char lds[32768];
    __shared__ float rmbuf[2][128];   // [wc][row_in_block]
    __shared__ float cmbuf[2][128];   // [wr][col_in_block]
    __shared__ float tbuf[4];
    char* ldsA = lds;
    char* ldsB = lds + 16384;
    const int tid = threadIdx.x;

    // bijective XCD swizzle (4096 blocks, 8 XCDs)
    const int lin = blockIdx.y * 64 + blockIdx.x;
    const int swz = (lin & 7) * 512 + (lin >> 3);
    const int bx = swz & 63, by = swz >> 6;
    const int rowBase = by * 128;
    const int colBase = bx * 128;

    const unsigned short* aG = (const unsigned short*)Ab + (size_t)rowBase * DD;
    const unsigned short* bG = (const unsigned short*)Bb + (size_t)colBase * DD;

    const int l = tid & 63, wid = tid >> 6;
    const int wr = wid >> 1, wc = wid & 1;   // wave 64x64 sub-tile
    const int g = l >> 4, c = l & 15;

    f32x4 acc[4][4];
#pragma unroll
    for (int mi = 0; mi < 4; ++mi)
#pragma unroll
        for (int ni = 0; ni < 4; ++ni) acc[mi][ni] = (f32x4)0.f;

#pragma unroll
    for (int p = 0; p < 2; ++p) {
        if (p) __syncthreads();   // previous compute done before overwrite
        // stage 128 rows x 64 bf16 (128 B/row) of A and B, XOR-swizzled
#pragma unroll
        for (int it = 0; it < 4; ++it) {
            int idx = tid + 256 * it;   // 0..1023
            int r = idx >> 3;           // row 0..127
            int c16 = idx & 7;          // 16B chunk in row
            int dst = r * 128 + ((c16 * 16) ^ ((r & 7) << 4));
            *(short8*)(ldsA + dst) = *(const short8*)(aG + r * DD + p * 64 + c16 * 8);
            *(short8*)(ldsB + dst) = *(const short8*)(bG + r * DD + p * 64 + c16 * 8);
        }
        __syncthreads();
#pragma unroll
        for (int kk = 0; kk < 2; ++kk) {
            short8 af[4], bf[4];
            const int kbyte = kk * 64 + g * 16;
#pragma unroll
            for (int mi = 0; mi < 4; ++mi) {
                int r = wr * 64 + mi * 16 + c;
                af[mi] = *(const short8*)(ldsA + r * 128 + (kbyte ^ ((r & 7) << 4)));
                int r2 = wc * 64 + mi * 16 + c;
                bf[mi] = *(const short8*)(ldsB + r2 * 128 + (kbyte ^ ((r2 & 7) << 4)));
            }
#pragma unroll
            for (int mi = 0; mi < 4; ++mi)
#pragma unroll
                for (int ni = 0; ni < 4; ++ni)
                    acc[mi][ni] = __builtin_amdgcn_mfma_f32_16x16x32_bf16(
                        af[mi], bf[ni], acc[mi][ni], 0, 0, 0);
        }
    }

    // out_row = row0 + mi*16 + g*4 + reg ; out_col = col0 + ni*16 + c
    const int row0 = rowBase + wr * 64;
    const int col0 = colBase + wc * 64;

    float nbc[4];
#pragma unroll
    for (int ni = 0; ni < 4; ++ni) nbc[ni] = nb[col0 + ni * 16 + c];

    float colm2[4] = {BIGF, BIGF, BIGF, BIGF};
    f32x4 tot4 = (f32x4)0.f;
#pragma unroll
    for (int mi = 0; mi < 4; ++mi) {
        const f32x4 na4 = *(const f32x4*)(na + row0 + mi * 16 + g * 4);
        float rowm2[4] = {BIGF, BIGF, BIGF, BIGF};
#pragma unroll
        for (int ni = 0; ni < 4; ++ni) {
            f32x4 a = acc[mi][ni];
#pragma unroll
            for (int reg = 0; reg < 4; ++reg) {
                float d2 = fmaf(-2.0f, a[reg], na4[reg] + nbc[ni]);
                rowm2[reg] = fminf(rowm2[reg], d2);
                colm2[ni] = fminf(colm2[ni], d2);
                tot4[reg] += __builtin_amdgcn_sqrtf(fmaxf(d2, 0.f));
            }
        }
        // row d^2 mins: reduce across the 16 c-lanes
#pragma unroll
        for (int reg = 0; reg < 4; ++reg) {
            float m = rowm2[reg];
            m = fminf(m, __shfl_xor(m, 1, 64));
            m = fminf(m, __shfl_xor(m, 2, 64));
            m = fminf(m, __shfl_xor(m, 4, 64));
            m = fminf(m, __shfl_xor(m, 8, 64));
            if (c == 0) rmbuf[wc][wr * 64 + mi * 16 + g * 4 + reg] = m;
        }
    }
    // col d^2 mins: reduce across the 4 g-groups
#pragma unroll
    for (int ni = 0; ni < 4; ++ni) {
        float m = colm2[ni];
        m = fminf(m, __shfl_xor(m, 16, 64));
        m = fminf(m, __shfl_xor(m, 32, 64));
        if (g == 0) cmbuf[wr][wc * 64 + ni * 16 + c] = m;
    }
    // grand total: wave reduce
    float tot = (tot4[0] + tot4[1]) + (tot4[2] + tot4[3]);
#pragma unroll
    for (int off = 32; off >= 1; off >>= 1) tot += __shfl_xor(tot, off, 64);
    if (l == 0) tbuf[wid] = tot;
    __syncthreads();

    // plain disjoint stores - no atomics anywhere
    if (tid < 128) {
        rowpart[(size_t)bx * NN + rowBase + tid] = fminf(rmbuf[0][tid], rmbuf[1][tid]);
    } else if (tid < 256) {
        int j = tid - 128;
        colpart[(size_t)by * NN + colBase + j] = fminf(cmbuf[0][j], cmbuf[1][j]);
    }
    if (tid == 0)
        totpart[by * 64 + bx] = tbuf[0] + tbuf[1] + tbuf[2] + tbuf[3];
}

// ---------------- fin: fold 64-way partials; one atomicAdd per block ----------------
// (64 float atomicAdds into out: ordering jitter ~1 ulp << 8.4e-2 threshold.
//  Visibility of dist's plain stores is by kernel boundary - no handshakes, R15 lesson.)
__global__ __launch_bounds__(256) void fin_kernel(const float* __restrict__ rowpart,
                                                  const float* __restrict__ colpart,
                                                  const float* __restrict__ totpart,
                                                  float* __restrict__ out) {
    const int idx = blockIdx.x * 256 + threadIdx.x;   // 0..16383
    const int j = (idx < NN) ? idx : idx - NN;
    const float* p = (idx < NN) ? rowpart : colpart;
    float m = BIGF;
#pragma unroll 8
    for (int k = 0; k < 64; ++k) m = fminf(m, p[(size_t)k * NN + j]);
    float contrib = -__builtin_amdgcn_sqrtf(fmaxf(m, 0.f)) * (1.0f / 16384.0f);
    if (blockIdx.x < 16)
        contrib += totpart[blockIdx.x * 256 + threadIdx.x] * (1.0f / 67108864.0f);
#pragma unroll
    for (int off = 32; off >= 1; off >>= 1) contrib += __shfl_xor(contrib, off, 64);
    __shared__ float red[4];
    if ((threadIdx.x & 63) == 0) red[threadIdx.x >> 6] = contrib;
    __syncthreads();
    if (threadIdx.x == 0)
        atomicAdd(out, red[0] + red[1] + red[2] + red[3]);
}

extern "C" void kernel_launch(void* const* d_in, const int* in_sizes, int n_in,
                              void* d_out, int out_size, void* d_ws, size_t ws_size,
                              hipStream_t stream) {
    const float* A = (const float*)d_in[0];
    const float* B = (const float*)d_in[1];
    char* ws = (char*)d_ws;

    const size_t MB = 1024 * 1024;
    __hip_bfloat16* Abf = (__hip_bfloat16*)(ws);                  // 2 MB
    __hip_bfloat16* Bbf = (__hip_bfloat16*)(ws + 2 * MB);         // 2 MB
    float* na      = (float*)(ws + 4 * MB);                       // 32 KB
    float* nb      = (float*)(ws + 4 * MB + 32768);               // 32 KB
    float* rowpart = (float*)(ws + 4 * MB + 65536);               // 2 MB  [ct][8192]
    float* colpart = (float*)(ws + 6 * MB + 65536);               // 2 MB  [rt][8192]
    float* totpart = (float*)(ws + 8 * MB + 65536);               // 16 KB

    dim3 pgrid(NN / 8, 2);
    prep_kernel<<<pgrid, 256, 0, stream>>>(A, B, Abf, Bbf, na, nb, (float*)d_out);

    dim3 grid(NN / 128, NN / 128);
    dist_fused<<<grid, 256, 0, stream>>>(Abf, Bbf, na, nb, rowpart, colpart, totpart);

    fin_kernel<<<64, 256, 0, stream>>>(rowpart, colpart, totpart, (float*)d_out);
}